// Round 2
// baseline (165.470 us; speedup 1.0000x reference)
//
#include <hip/hip_runtime.h>
#include <math.h>

constexpr int K = 512;
constexpr int D = 64;
constexpr int HW = 64 * 64;                      // 4096
constexpr int NPIX = 131072;
constexpr long long NELEM = (long long)NPIX * D; // 8388608
constexpr float BETA = 0.25f;
constexpr int PPB = 128;                         // pixels per block
constexpr int NBLK = NPIX / PPB;                 // 1024 blocks (4 per CU)
constexpr int NT = PPB / 16;                     // 8 A-tiles per block

typedef __attribute__((ext_vector_type(8))) short short8;
typedef __attribute__((ext_vector_type(4))) float f32x4;

union frag_u { uint4 u; short8 s; };

__device__ inline unsigned short bf16rne(float x) {
    unsigned u = __float_as_uint(x);
    unsigned r = (u + 0x7FFFu + ((u >> 16) & 1u)) >> 16;
    return (unsigned short)r;
}

// truncated-bf16 pack: f0 -> low ushort, f1 -> high ushort (one v_perm_b32)
__device__ inline unsigned pk(float f0, float f1) {
    return __builtin_amdgcn_perm(__float_as_uint(f1), __float_as_uint(f0), 0x07060302u);
}

// K-split restructure: each wave owns 64 codes (B-frags in REGISTERS, ~36 VGPR),
// A-tiles staged in LDS bf16 (16 KB). LDS ~20 KB -> 3-4 blocks/CU (vs 2 before).
// Cross-wave argmin via per-pixel LDS atomicMin on monotone-mapped keys.
__global__ __launch_bounds__(512, 6) void vq_one(
    const float* __restrict__ z, const float* __restrict__ E,
    float* __restrict__ out, int out_size, float* __restrict__ sse_arr,
    unsigned int* __restrict__ counts, unsigned int* __restrict__ ticket) {

    __shared__ __align__(16) unsigned short sa[PPB * D];  // 16 KB A-frags bf16
    __shared__ float zsq_s[PPB];
    __shared__ unsigned int best_s[PPB];
    __shared__ int bks[PPB];
    __shared__ unsigned int hcnt[K];
    __shared__ float red[8], red2[8];
    __shared__ int sflag;

    const int tid = threadIdx.x;
    const int wave = tid >> 6;      // 0..7
    const int lane = tid & 63;
    const int q = lane >> 4;        // k-quad
    const int lx = lane & 15;       // m for A, n for B, col for C/D

    const int p0 = blockIdx.x * PPB;
    const int b = p0 >> 12;
    const int s0 = p0 & (HW - 1);

    hcnt[tid] = 0u;
    if (tid < PPB) best_s[tid] = 0xFFFFFFFFu;

    // ---- A loads: 16 scattered dwords (pixel = wave*16+lx, d = c*32+q*8+j),
    //      issued early; consumed (packed) after B-build overlaps the latency ----
    const float* zb = z + (size_t)b * (D * HW) + s0 + wave * 16;
    float z0[16];
#pragma unroll
    for (int c = 0; c < 2; ++c)
#pragma unroll
        for (int j = 0; j < 8; ++j)
            z0[c * 8 + j] = zb[(size_t)(c * 32 + q * 8 + j) * HW + lx];

    // ---- B build: this wave's 64 codes -> register frags (4 col-tiles) ----
    const int nb = wave * 64;
    frag_u bf[4][2];
    unsigned beec[4];
#pragma unroll
    for (int ct = 0; ct < 4; ++ct) {
        const float* er = E + (size_t)(nb + ct * 16 + lx) * D + q * 8;
        float4 c0 = *(const float4*)(er + 0);
        float4 c1 = *(const float4*)(er + 4);
        float4 c2 = *(const float4*)(er + 32);
        float4 c3 = *(const float4*)(er + 36);
        float ss = 0.f;
        ss = fmaf(c0.x, c0.x, ss); ss = fmaf(c0.y, c0.y, ss);
        ss = fmaf(c0.z, c0.z, ss); ss = fmaf(c0.w, c0.w, ss);
        ss = fmaf(c1.x, c1.x, ss); ss = fmaf(c1.y, c1.y, ss);
        ss = fmaf(c1.z, c1.z, ss); ss = fmaf(c1.w, c1.w, ss);
        ss = fmaf(c2.x, c2.x, ss); ss = fmaf(c2.y, c2.y, ss);
        ss = fmaf(c2.z, c2.z, ss); ss = fmaf(c2.w, c2.w, ss);
        ss = fmaf(c3.x, c3.x, ss); ss = fmaf(c3.y, c3.y, ss);
        ss = fmaf(c3.z, c3.z, ss); ss = fmaf(c3.w, c3.w, ss);
        bf[ct][0].u.x = pk(-2.f * c0.x, -2.f * c0.y);
        bf[ct][0].u.y = pk(-2.f * c0.z, -2.f * c0.w);
        bf[ct][0].u.z = pk(-2.f * c1.x, -2.f * c1.y);
        bf[ct][0].u.w = pk(-2.f * c1.z, -2.f * c1.w);
        bf[ct][1].u.x = pk(-2.f * c2.x, -2.f * c2.y);
        bf[ct][1].u.y = pk(-2.f * c2.z, -2.f * c2.w);
        bf[ct][1].u.z = pk(-2.f * c3.x, -2.f * c3.y);
        bf[ct][1].u.w = pk(-2.f * c3.z, -2.f * c3.w);
        // full ||e||^2: sum the 4 k-quads across lanes (same lx, same ct)
        ss += __shfl_xor(ss, 16, 64);
        ss += __shfl_xor(ss, 32, 64);
        unsigned short eh = bf16rne(ss);
        unsigned short el = bf16rne(ss - __uint_as_float((unsigned)eh << 16));
        beec[ct] = (unsigned)eh | ((unsigned)el << 16);
    }

    // ---- A pack + fp32 ||z||^2 + stage to LDS in frag layout ----
    {
        float zq2 = 0.f;
#pragma unroll
        for (int i = 0; i < 16; ++i) zq2 = fmaf(z0[i], z0[i], zq2);
        frag_u a0, a1;
        a0.u.x = pk(z0[0], z0[1]);   a0.u.y = pk(z0[2], z0[3]);
        a0.u.z = pk(z0[4], z0[5]);   a0.u.w = pk(z0[6], z0[7]);
        a1.u.x = pk(z0[8], z0[9]);   a1.u.y = pk(z0[10], z0[11]);
        a1.u.z = pk(z0[12], z0[13]); a1.u.w = pk(z0[14], z0[15]);
        *(uint4*)&sa[wave * 1024 + lane * 8] = a0.u;
        *(uint4*)&sa[wave * 1024 + 512 + lane * 8] = a1.u;
        zq2 += __shfl_xor(zq2, 16, 64);
        zq2 += __shfl_xor(zq2, 32, 64);
        if (q == 0) zsq_s[wave * 16 + lx] = zq2;
    }

    frag_u aee;
    aee.u.x = (q == 0) ? 0x3F803F80u : 0u;
    aee.u.y = 0u; aee.u.z = 0u; aee.u.w = 0u;

    __syncthreads();   // sa + zsq_s + best_s init resident

    // ---- Main loop: 8 A-tiles x this wave's 4 col-tiles ----
#pragma unroll 1
    for (int t = 0; t < NT; ++t) {
        frag_u A0, A1;
        A0.u = *(const uint4*)&sa[t * 1024 + lane * 8];
        A1.u = *(const uint4*)&sa[t * 1024 + 512 + lane * 8];
        float best4[4];
#pragma unroll
        for (int r = 0; r < 4; ++r) best4[r] = __uint_as_float(0x7F800000u);
#pragma unroll
        for (int ct = 0; ct < 4; ++ct) {
            frag_u bee;
            bee.u.x = (q == 0) ? beec[ct] : 0u;
            bee.u.y = 0u; bee.u.z = 0u; bee.u.w = 0u;
            f32x4 acc = {0.f, 0.f, 0.f, 0.f};
            acc = __builtin_amdgcn_mfma_f32_16x16x32_bf16(A0.s, bf[ct][0].s, acc, 0, 0, 0);
            acc = __builtin_amdgcn_mfma_f32_16x16x32_bf16(A1.s, bf[ct][1].s, acc, 0, 0, 0);
            acc = __builtin_amdgcn_mfma_f32_16x16x32_bf16(aee.s, bee.s, acc, 0, 0, 0);
            unsigned col = (unsigned)(nb + ct * 16 + lx);
#pragma unroll
            for (int r = 0; r < 4; ++r) {
                float kk = __uint_as_float((__float_as_uint(acc[r]) & 0xFFFFFE00u) | col);
                best4[r] = fminf(best4[r], kk);
            }
        }
        // butterfly min over the 16 code-columns, then one writer per pixel row
#pragma unroll
        for (int r = 0; r < 4; ++r) {
            float v = best4[r];
#pragma unroll
            for (int m = 1; m < 16; m <<= 1) v = fminf(v, __shfl_xor(v, m, 64));
            if (lx == q * 4 + r) {
                unsigned u = __float_as_uint(v);
                unsigned key = u ^ (((unsigned)((int)u >> 31)) | 0x80000000u);
                atomicMin(&best_s[t * 16 + q * 4 + r], key);
            }
        }
    }

    __syncthreads();   // all waves' atomicMin done

    // ---- Decode per-pixel winner: histogram + SSE ----
    float lsse = 0.f;
    if (tid < PPB) {
        unsigned key = best_s[tid];
        unsigned orig = (key & 0x80000000u) ? (key ^ 0x80000000u) : ~key;
        int code = (int)(orig & 0x1FFu);
        bks[tid] = code;
        atomicAdd(&hcnt[code], 1u);
        lsse = zsq_s[tid] + __uint_as_float(orig & 0xFFFFFE00u);
    }
#pragma unroll
    for (int off = 32; off > 0; off >>= 1) lsse += __shfl_down(lsse, off, 64);
    if (lane == 0) red[wave] = lsse;

    __syncthreads();   // bks + red visible
    if (tid == 0) {
        float s = 0.f;
#pragma unroll
        for (int i = 0; i < 8; ++i) s += red[i];
        sse_arr[blockIdx.x] = s;
    }

    // ---- Epilogue: thread -> (pixel = tid&127, d-quarter = tid>>7) ----
    {
        int qp = tid & (PPB - 1);
        int dq = tid >> 7;          // 0..3
        int bk = bks[qp];
        const float4* Er = (const float4*)(E + (size_t)bk * D + dq * 16);
        float* ob = out + 1 + (size_t)b * (D * HW) + (size_t)dq * 16 * HW + s0 + qp;
#pragma unroll
        for (int v4i = 0; v4i < 4; ++v4i) {
            float4 e4 = Er[v4i];
            ob[(size_t)(4 * v4i + 0) * HW] = e4.x;
            ob[(size_t)(4 * v4i + 1) * HW] = e4.y;
            ob[(size_t)(4 * v4i + 2) * HW] = e4.z;
            ob[(size_t)(4 * v4i + 3) * HW] = e4.w;
        }
    }

    // ---- flush histogram ----
    unsigned hc = hcnt[tid];
    if (hc) atomicAdd(&counts[tid], hc);

    // ---- fused finalize: last block computes loss + perplexity ----
    __syncthreads();
    if (tid == 0) {
        __threadfence();
        unsigned t = atomicAdd(ticket, 1u);
        sflag = (t == (unsigned)(NBLK - 1)) ? 1 : 0;
    }
    __syncthreads();
    if (sflag) {
        float cf = (float)atomicAdd(&counts[tid], 0u);
        float pa = cf / (float)NPIX + 1e-10f;
        float t = pa * logf(pa);
        float s = atomicAdd(&sse_arr[tid], 0.0f) + atomicAdd(&sse_arr[tid + 512], 0.0f);
#pragma unroll
        for (int off = 32; off > 0; off >>= 1) {
            t += __shfl_down(t, off, 64);
            s += __shfl_down(s, off, 64);
        }
        if (lane == 0) { red[wave] = t; red2[wave] = s; }
        __syncthreads();
        if (tid == 0) {
            float tot = 0.f, st = 0.f;
#pragma unroll
            for (int i = 0; i < 8; ++i) { tot += red[i]; st += red2[i]; }
            out[0] = (1.f + BETA) * st / (float)NELEM;
            out[out_size - 1] = expf(-tot);
        }
    }
}

extern "C" void kernel_launch(void* const* d_in, const int* in_sizes, int n_in,
                              void* d_out, int out_size, void* d_ws, size_t ws_size,
                              hipStream_t stream) {
    const float* z = (const float*)d_in[0];
    const float* E = (const float*)d_in[1];
    float* out = (float*)d_out;

    float* wsf = (float*)d_ws;
    unsigned int* ticket = (unsigned int*)wsf;         // [0] (+pad)
    unsigned int* counts = (unsigned int*)(wsf + 4);   // 512 uints
    float* sse_arr = wsf + 4 + K;                      // 1024 floats (one per block)

    hipMemsetAsync(d_ws, 0, (4 + K) * sizeof(float), stream);   // ticket + counts
    vq_one<<<NBLK, 512, 0, stream>>>(z, E, out, out_size, sse_arr, counts, ticket);
}

// Round 3
// 153.389 us; speedup vs baseline: 1.0788x; 1.0788x over previous
//
#include <hip/hip_runtime.h>
#include <math.h>

constexpr int K = 512;
constexpr int D = 64;
constexpr int HW = 64 * 64;                      // 4096
constexpr int NPIX = 131072;
constexpr long long NELEM = (long long)NPIX * D; // 8388608
constexpr float BETA = 0.25f;
constexpr int PPB = 128;                         // pixels per block
constexpr int NBLK = NPIX / PPB;                 // 1024 blocks (4 per CU)

typedef __attribute__((ext_vector_type(8))) short short8;
typedef __attribute__((ext_vector_type(4))) float f32x4;

union frag_u { uint4 u; short8 s; };

__device__ inline unsigned short bf16rne(float x) {
    unsigned u = __float_as_uint(x);
    unsigned r = (u + 0x7FFFu + ((u >> 16) & 1u)) >> 16;
    return (unsigned short)r;
}

// truncated-bf16 pack: f0 -> low ushort, f1 -> high ushort (one v_perm_b32)
__device__ inline unsigned pk(float f0, float f1) {
    return __builtin_amdgcn_perm(__float_as_uint(f1), __float_as_uint(f0), 0x07060302u);
}

// ---- Prep: build bf16 B-frags (-2*E) + packed ||e||^2 hi/lo into workspace.
// Exact same arithmetic/order as the verified in-kernel B build.
__global__ void vq_prep(const float* __restrict__ E,
                        uint4* __restrict__ gsb, unsigned* __restrict__ eepk) {
    const int n = blockIdx.x * 128 + threadIdx.x;   // 0..511
    const float4* er = (const float4*)(E + (size_t)n * D);
    const int tile = n >> 4, col = n & 15;
    float acc = 0.f;
#pragma unroll
    for (int g = 0; g < 8; ++g) {
        float4 c0 = er[2 * g], c1 = er[2 * g + 1];
        acc = fmaf(c0.x, c0.x, acc); acc = fmaf(c0.y, c0.y, acc);
        acc = fmaf(c0.z, c0.z, acc); acc = fmaf(c0.w, c0.w, acc);
        acc = fmaf(c1.x, c1.x, acc); acc = fmaf(c1.y, c1.y, acc);
        acc = fmaf(c1.z, c1.z, acc); acc = fmaf(c1.w, c1.w, acc);
        uint4 w;
        w.x = pk(-2.f * c0.x, -2.f * c0.y);
        w.y = pk(-2.f * c0.z, -2.f * c0.w);
        w.z = pk(-2.f * c1.x, -2.f * c1.y);
        w.w = pk(-2.f * c1.z, -2.f * c1.w);
        // uint4 index = ushort offset / 8 of old layout
        gsb[(tile * 2 + (g >> 2)) * 64 + ((g & 3) * 16 + col)] = w;
    }
    unsigned short eh = bf16rne(acc);
    unsigned short el = bf16rne(acc - __uint_as_float((unsigned)eh << 16));
    eepk[n] = (unsigned)eh | ((unsigned)el << 16);
}

// ---- Main: A in regs, full-K per wave, B-frags streamed from global (L2).
// LDS ~2.6 KB -> residency grid-limited at 4 blocks/CU; (256,4) = 128-reg cap.
__global__ __launch_bounds__(256, 4) void vq_main(
    const float* __restrict__ z, const float* __restrict__ E,
    float* __restrict__ out, int out_size,
    const uint4* __restrict__ gsb, const unsigned* __restrict__ eepk,
    float* __restrict__ sse_arr, unsigned int* __restrict__ counts,
    unsigned int* __restrict__ ticket) {

    __shared__ int bks[PPB];
    __shared__ unsigned int hcnt[K];
    __shared__ float red[4], red2[4];
    __shared__ int sflag;

    const int tid = threadIdx.x;
    const int wave = tid >> 6;      // 0..3
    const int lane = tid & 63;
    const int quad = lane >> 4;     // k-group
    const int lx = lane & 15;       // m for A, n for B, col for C/D

    const int p0 = blockIdx.x * PPB;
    const int b = p0 >> 12;
    const int s0 = p0 & (HW - 1);

    hcnt[tid] = 0u;
    hcnt[tid + 256] = 0u;

    // ---- A loads (32 scattered dwords, issued early) ----
    const float* zb = z + (size_t)b * (D * HW) + s0 + wave * 32;
    float z0[16], z1[16];   // row-tile 0 / 1
#pragma unroll
    for (int c = 0; c < 2; ++c)
#pragma unroll
        for (int j = 0; j < 8; ++j) {
            size_t doff = (size_t)(c * 32 + quad * 8 + j) * HW;
            z0[c * 8 + j] = zb[doff + lx];
            z1[c * 8 + j] = zb[doff + 16 + lx];
        }

    // ---- A pack + exact fp32 ||z||^2 ----
    frag_u a[2][2];
    float zsq = 0.f;
#pragma unroll
    for (int c = 0; c < 2; ++c) {
#pragma unroll
        for (int j = 0; j < 8; ++j) {
            zsq = fmaf(z0[c * 8 + j], z0[c * 8 + j], zsq);
            zsq = fmaf(z1[c * 8 + j], z1[c * 8 + j], zsq);
        }
        a[0][c].u.x = pk(z0[c * 8 + 0], z0[c * 8 + 1]);
        a[0][c].u.y = pk(z0[c * 8 + 2], z0[c * 8 + 3]);
        a[0][c].u.z = pk(z0[c * 8 + 4], z0[c * 8 + 5]);
        a[0][c].u.w = pk(z0[c * 8 + 6], z0[c * 8 + 7]);
        a[1][c].u.x = pk(z1[c * 8 + 0], z1[c * 8 + 1]);
        a[1][c].u.y = pk(z1[c * 8 + 2], z1[c * 8 + 3]);
        a[1][c].u.z = pk(z1[c * 8 + 4], z1[c * 8 + 5]);
        a[1][c].u.w = pk(z1[c * 8 + 6], z1[c * 8 + 7]);
    }

    // ee fold-in A operand: k slots 0,1 = 1.0 (quad 0 only)
    frag_u aee;
    aee.u.x = (quad == 0) ? 0x3F803F80u : 0u;
    aee.u.y = 0u; aee.u.z = 0u; aee.u.w = 0u;

    float best0[4], best1[4];
#pragma unroll
    for (int r = 0; r < 4; ++r) {
        best0[r] = __uint_as_float(0x7F800000u);
        best1[r] = __uint_as_float(0x7F800000u);
    }

    __syncthreads();   // hcnt init visible before argmin-phase atomics

    // ---- Main loop: 16 x 2 col-tiles, B from global with 1-iter prefetch ----
    frag_u ba0, ba1, bb0, bb1;
    unsigned cea, ceb;
    ba0.u = gsb[0 * 64 + lane];
    ba1.u = gsb[1 * 64 + lane];
    bb0.u = gsb[2 * 64 + lane];
    bb1.u = gsb[3 * 64 + lane];
    cea = eepk[lx];
    ceb = eepk[16 + lx];

#pragma unroll 1
    for (int t2 = 0; t2 < 16; ++t2) {
        const int tn = (t2 + 1) & 15;          // wrap: avoids branch, read is benign
        frag_u na0, na1, nb0, nb1;
        na0.u = gsb[(4 * tn + 0) * 64 + lane];
        na1.u = gsb[(4 * tn + 1) * 64 + lane];
        nb0.u = gsb[(4 * tn + 2) * 64 + lane];
        nb1.u = gsb[(4 * tn + 3) * 64 + lane];
        unsigned nea = eepk[2 * tn * 16 + lx];
        unsigned neb = eepk[(2 * tn + 1) * 16 + lx];

        frag_u beea, beeb;
        beea.u.x = (quad == 0) ? cea : 0u;
        beea.u.y = 0u; beea.u.z = 0u; beea.u.w = 0u;
        beeb.u.x = (quad == 0) ? ceb : 0u;
        beeb.u.y = 0u; beeb.u.z = 0u; beeb.u.w = 0u;

        f32x4 aa0 = {0,0,0,0}, aa1 = {0,0,0,0}, ab0 = {0,0,0,0}, ab1 = {0,0,0,0};
        aa0 = __builtin_amdgcn_mfma_f32_16x16x32_bf16(a[0][0].s, ba0.s, aa0, 0, 0, 0);
        aa1 = __builtin_amdgcn_mfma_f32_16x16x32_bf16(a[1][0].s, ba0.s, aa1, 0, 0, 0);
        ab0 = __builtin_amdgcn_mfma_f32_16x16x32_bf16(a[0][0].s, bb0.s, ab0, 0, 0, 0);
        ab1 = __builtin_amdgcn_mfma_f32_16x16x32_bf16(a[1][0].s, bb0.s, ab1, 0, 0, 0);
        aa0 = __builtin_amdgcn_mfma_f32_16x16x32_bf16(a[0][1].s, ba1.s, aa0, 0, 0, 0);
        aa1 = __builtin_amdgcn_mfma_f32_16x16x32_bf16(a[1][1].s, ba1.s, aa1, 0, 0, 0);
        ab0 = __builtin_amdgcn_mfma_f32_16x16x32_bf16(a[0][1].s, bb1.s, ab0, 0, 0, 0);
        ab1 = __builtin_amdgcn_mfma_f32_16x16x32_bf16(a[1][1].s, bb1.s, ab1, 0, 0, 0);
        aa0 = __builtin_amdgcn_mfma_f32_16x16x32_bf16(aee.s, beea.s, aa0, 0, 0, 0);
        aa1 = __builtin_amdgcn_mfma_f32_16x16x32_bf16(aee.s, beea.s, aa1, 0, 0, 0);
        ab0 = __builtin_amdgcn_mfma_f32_16x16x32_bf16(aee.s, beeb.s, ab0, 0, 0, 0);
        ab1 = __builtin_amdgcn_mfma_f32_16x16x32_bf16(aee.s, beeb.s, ab1, 0, 0, 0);

        unsigned cba = (unsigned)(2 * t2 * 16 + lx);
        unsigned cbb = (unsigned)((2 * t2 + 1) * 16 + lx);
#pragma unroll
        for (int r = 0; r < 4; ++r) {
            float ka0 = __uint_as_float((__float_as_uint(aa0[r]) & 0xFFFFFE00u) | cba);
            float kb0 = __uint_as_float((__float_as_uint(ab0[r]) & 0xFFFFFE00u) | cbb);
            best0[r] = fminf(fminf(best0[r], ka0), kb0);
            float ka1 = __uint_as_float((__float_as_uint(aa1[r]) & 0xFFFFFE00u) | cba);
            float kb1 = __uint_as_float((__float_as_uint(ab1[r]) & 0xFFFFFE00u) | cbb);
            best1[r] = fminf(fminf(best1[r], ka1), kb1);
        }

        ba0 = na0; ba1 = na1; bb0 = nb0; bb1 = nb1;
        cea = nea; ceb = neb;
    }

    // ---- Cross-lane argmin (butterfly over low 4 lane bits) + SSE ----
    float lsse = zsq;
#pragma unroll
    for (int rt = 0; rt < 2; ++rt) {
#pragma unroll
        for (int r = 0; r < 4; ++r) {
            float v = rt == 0 ? best0[r] : best1[r];
#pragma unroll
            for (int m = 1; m < 16; m <<= 1) v = fminf(v, __shfl_xor(v, m, 64));
            if (lx == 4 * quad + r) {   // one writer per (quad,r): row = 4*quad+r
                unsigned u = __float_as_uint(v);
                int c = (int)(u & 0x1FFu);
                bks[wave * 32 + rt * 16 + 4 * quad + r] = c;
                atomicAdd(&hcnt[c], 1u);
                lsse += __uint_as_float(u & 0xFFFFFE00u);
            }
        }
    }
#pragma unroll
    for (int off = 32; off > 0; off >>= 1) lsse += __shfl_down(lsse, off, 64);
    if (lane == 0) red[wave] = lsse;

    __syncthreads();
    if (tid == 0) {
        float s = 0.f;
#pragma unroll
        for (int i = 0; i < 4; ++i) s += red[i];
        sse_arr[blockIdx.x] = s;
    }

    // ---- Epilogue: thread -> (pixel = tid&127, d-half = tid>>7) ----
    {
        int q = tid & (PPB - 1);
        int dh = tid >> 7;          // 0..1
        int bk = bks[q];
        const float4* Er = (const float4*)(E + (size_t)bk * D + dh * 32);
        float* ob = out + 1 + (size_t)b * (D * HW) + (size_t)dh * 32 * HW + s0 + q;
#pragma unroll
        for (int v4i = 0; v4i < 8; ++v4i) {
            float4 e4 = Er[v4i];
            ob[(size_t)(4 * v4i + 0) * HW] = e4.x;
            ob[(size_t)(4 * v4i + 1) * HW] = e4.y;
            ob[(size_t)(4 * v4i + 2) * HW] = e4.z;
            ob[(size_t)(4 * v4i + 3) * HW] = e4.w;
        }
    }

    // ---- flush histogram ----
    {
        unsigned hc0 = hcnt[tid];
        if (hc0) atomicAdd(&counts[tid], hc0);
        unsigned hc1 = hcnt[tid + 256];
        if (hc1) atomicAdd(&counts[tid + 256], hc1);
    }

    // ---- fused finalize: last block computes loss + perplexity ----
    __syncthreads();
    if (tid == 0) {
        __threadfence();
        unsigned t = atomicAdd(ticket, 1u);
        sflag = (t == (unsigned)(NBLK - 1)) ? 1 : 0;
    }
    __syncthreads();
    if (sflag) {
        float t = 0.f, s = 0.f;
#pragma unroll
        for (int i = 0; i < 2; ++i) {
            float cf = (float)atomicAdd(&counts[tid + 256 * i], 0u);
            float pa = cf / (float)NPIX + 1e-10f;
            t += pa * logf(pa);
        }
#pragma unroll
        for (int i = 0; i < 4; ++i)
            s += atomicAdd(&sse_arr[tid + 256 * i], 0.0f);
#pragma unroll
        for (int off = 32; off > 0; off >>= 1) {
            t += __shfl_down(t, off, 64);
            s += __shfl_down(s, off, 64);
        }
        if (lane == 0) { red[wave] = t; red2[wave] = s; }
        __syncthreads();
        if (tid == 0) {
            float tot = 0.f, st = 0.f;
#pragma unroll
            for (int i = 0; i < 4; ++i) { tot += red[i]; st += red2[i]; }
            out[0] = (1.f + BETA) * st / (float)NELEM;
            out[out_size - 1] = expf(-tot);
        }
    }
}

extern "C" void kernel_launch(void* const* d_in, const int* in_sizes, int n_in,
                              void* d_out, int out_size, void* d_ws, size_t ws_size,
                              hipStream_t stream) {
    const float* z = (const float*)d_in[0];
    const float* E = (const float*)d_in[1];
    float* out = (float*)d_out;

    unsigned int* base = (unsigned int*)d_ws;
    unsigned int* ticket = base;                        // [0..3]
    unsigned int* counts = base + 4;                    // 512 uints
    float* sse_arr = (float*)(base + 4 + K);            // 1024 floats
    uint4* gsb = (uint4*)(base + 4 + K + NBLK);         // 64 KB B-frags (16-B aligned)
    unsigned int* eepk = base + 4 + K + NBLK + 4096 * 4; // 512 uints

    hipMemsetAsync(d_ws, 0, (4 + K) * sizeof(unsigned int), stream);  // ticket + counts
    vq_prep<<<4, 128, 0, stream>>>(E, gsb, eepk);
    vq_main<<<NBLK, 256, 0, stream>>>(z, E, out, out_size, gsb, eepk,
                                      sse_arr, counts, ticket);
}